// Round 18
// baseline (148.624 us; speedup 1.0000x reference)
//
#include <hip/hip_runtime.h>
#include <hip/hip_bf16.h>

#define DIM 768
#define NH 12
#define HD 64
#define NSEQ 1568
#define ROWS 6272          // B*NSEQ
#define QSC2 0.18033688011112042f   // 0.125 * log2(e) -> softmax in exp2 domain
#define RGN 100352         // per-bh fragment region: 98*1024 = 49*2048 elems

typedef __attribute__((ext_vector_type(8))) short short8;
typedef __attribute__((ext_vector_type(4))) float f32x4;
typedef __attribute__((ext_vector_type(4))) unsigned short u16x4;
typedef unsigned short ushort_t;
typedef unsigned int uint_t;

static __device__ __forceinline__ ushort_t f2bf(float f) {
    union { float f; uint_t u; } c; c.f = f;
    uint_t u = c.u + 0x7fffu + ((c.u >> 16) & 1u);   // RNE
    return (ushort_t)(u >> 16);
}
static __device__ __forceinline__ int cvt_pk_bf16(float lo, float hi) {
    int r;
    asm("v_cvt_pk_bf16_f32 %0, %1, %2" : "=v"(r) : "v"(lo), "v"(hi));
    return r;
}
// async global->LDS, 16B per lane; LDS dest = wave-uniform base + lane*16
static __device__ __forceinline__ void glds16(const short* g, short* l) {
    __builtin_amdgcn_global_load_lds(
        (const __attribute__((address_space(1))) void*)g,
        (__attribute__((address_space(3))) void*)l, 16, 0, 0);
}

// softmax+pack+bperm for one q-half (no rowsum: l accumulated via ones-MFMA)
#define SM_HALF(S, PF)                                                        \
    {                                                                         \
        float p_[4][4];                                                       \
        _Pragma("unroll")                                                     \
        for (int jb = 0; jb < 4; ++jb) {                                      \
            _Pragma("unroll")                                                 \
            for (int r = 0; r < 4; ++r)                                       \
                p_[jb][r] = __builtin_amdgcn_exp2f(S[jb][r]);                 \
        }                                                                     \
        int pw_[4][2];                                                        \
        _Pragma("unroll")                                                     \
        for (int jb = 0; jb < 4; ++jb) {                                      \
            pw_[jb][0] = cvt_pk_bf16(p_[jb][0], p_[jb][1]);                   \
            pw_[jb][1] = cvt_pk_bf16(p_[jb][2], p_[jb][3]);                   \
        }                                                                     \
        _Pragma("unroll")                                                     \
        for (int jb2 = 0; jb2 < 2; ++jb2) {                                   \
            int S0_ = gh ? pw_[jb2 * 2 + 1][0] : pw_[jb2 * 2][0];             \
            int S1_ = gh ? pw_[jb2 * 2 + 1][1] : pw_[jb2 * 2][1];             \
            union { int i[4]; short8 s; } fr_;                                \
            fr_.i[0] = __builtin_amdgcn_ds_bpermute(addr0, S0_);              \
            fr_.i[1] = __builtin_amdgcn_ds_bpermute(addr0, S1_);              \
            fr_.i[2] = __builtin_amdgcn_ds_bpermute(addr1, S0_);              \
            fr_.i[3] = __builtin_amdgcn_ds_bpermute(addr1, S1_);              \
            PF[jb2] = fr_.s;                                                  \
        }                                                                     \
    }

// ---------------------------------------------------- fused prep+conv+cls --
#define PREP_HALF (ROWS * (DIM / 8))
#define W8 (DIM * DIM / 8)
#define CLS4 (32 * DIM / 4)
// total = 2*PREP_HALF + 4*W8 + CLS4 = 1505280 = 5880*256
__global__ __launch_bounds__(256)
void prep_all(const float* __restrict__ src_t, const float* __restrict__ src_s,
              const float* __restrict__ vsp, const float* __restrict__ csp,
              const float* __restrict__ vtp, const float* __restrict__ ctp,
              const float* __restrict__ qw, const float* __restrict__ kvw,
              const float* __restrict__ pw, const float* __restrict__ txc,
              short* __restrict__ dst_t, short* __restrict__ dst_s,
              short* __restrict__ dq, short* __restrict__ dkv,
              short* __restrict__ dp, float* __restrict__ out_cls) {
    int idx = blockIdx.x * 256 + threadIdx.x;
    if (idx < 2 * PREP_HALF) {
        int sel = idx >= PREP_HALF;
        int i0  = sel ? idx - PREP_HALF : idx;
        const float* src  = sel ? src_s : src_t;
        const float* spos = sel ? csp : vsp;
        const float* tpos = sel ? ctp : vtp;
        short* dst = sel ? dst_s : dst_t;
        int d8  = i0 % (DIM / 8);
        int row = i0 / (DIM / 8);
        int b = row / NSEQ;
        int i = row % NSEQ;
        int n = i >> 3;
        int t = i & 7;
        const float4* s4 = reinterpret_cast<const float4*>(src + ((size_t)n * 32 + b * 8 + t) * DIM + d8 * 8);
        const float4* p4 = reinterpret_cast<const float4*>(spos + (size_t)n * DIM + d8 * 8);
        const float4* q4 = reinterpret_cast<const float4*>(tpos + (size_t)t * DIM + d8 * 8);
        union { int w[4]; short8 v; } o;
        float4 a0 = s4[0], a1 = s4[1], b0 = p4[0], b1 = p4[1], c0 = q4[0], c1 = q4[1];
        o.w[0] = cvt_pk_bf16(a0.x + b0.x + c0.x, a0.y + b0.y + c0.y);
        o.w[1] = cvt_pk_bf16(a0.z + b0.z + c0.z, a0.w + b0.w + c0.w);
        o.w[2] = cvt_pk_bf16(a1.x + b1.x + c1.x, a1.y + b1.y + c1.y);
        o.w[3] = cvt_pk_bf16(a1.z + b1.z + c1.z, a1.w + b1.w + c1.w);
        reinterpret_cast<short8*>(dst)[i0] = o.v;
    } else if (idx < 2 * PREP_HALF + 4 * W8) {
        int i0 = idx - 2 * PREP_HALF;
        const float* src; short* dst; int off;
        if (i0 < W8)            { src = qw;  dst = dq;  off = i0; }
        else if (i0 < 3 * W8)   { src = kvw; dst = dkv; off = i0 - W8; }
        else                    { src = pw;  dst = dp;  off = i0 - 3 * W8; }
        const float4* s4 = reinterpret_cast<const float4*>(src + (size_t)off * 8);
        float4 a0 = s4[0], a1 = s4[1];
        union { int w[4]; short8 v; } o;
        o.w[0] = cvt_pk_bf16(a0.x, a0.y);
        o.w[1] = cvt_pk_bf16(a0.z, a0.w);
        o.w[2] = cvt_pk_bf16(a1.x, a1.y);
        o.w[3] = cvt_pk_bf16(a1.z, a1.w);
        reinterpret_cast<short8*>(dst)[off] = o.v;
    } else {
        int i0 = idx - (2 * PREP_HALF + 4 * W8);
        reinterpret_cast<float4*>(out_cls)[i0] = reinterpret_cast<const float4*>(txc)[i0];
    }
}

// ------------------------------------------------------ fused q+kv GEMM ---
// T4 counted-vmcnt two-barrier K-loop (R17-verified). Epilogue writes Q/K/V
// in MFMA-FRAGMENT-MAJOR layouts:
//   Q/K elem (bh,j,e) -> bh*RGN + (j>>4)*1024 + (e>>3)*128 + (j&15)*8 + (e&7)
//   V   elem (bh,d,m) -> bh*RGN + (m>>5)*2048 + (d>>4)*512
//                         + ((m&31)>>3)*128 + (d&15)*8 + (m&7)
__global__ __launch_bounds__(256)
void gemm_qkv(const short* __restrict__ tpat, const short* __restrict__ spat,
              const short* __restrict__ wq, const short* __restrict__ wkv,
              const float* __restrict__ q_b, const float* __restrict__ kv_b,
              ushort_t* __restrict__ qout, ushort_t* __restrict__ kout,
              ushort_t* __restrict__ vtout) {
    __shared__ short As[2][128 * 32];
    __shared__ short Ws[2][128 * 32];
    const int t = threadIdx.x;
    const int l = t & 63, w = t >> 6;
    const int Li = l & 15, Lg = l >> 4;
    int orig = blockIdx.x;                       // 882 blocks
    int xcd = orig & 7, idxq = orig >> 3;
    int wg = (xcd < 2 ? xcd * 111 : 222 + (xcd - 2) * 110) + idxq;
    const int x = wg % 18, y = wg / 18;
    const int mode = (x >= 6);
    const short* A  = mode ? spat : tpat;
    const short* Wm = mode ? wkv : wq;
    const float* bias = mode ? kv_b : q_b;
    const int c0 = (mode ? x - 6 : x) * 128;
    const int r0 = y * 128;
    const int wrow = (w >> 1) * 64, wcol = (w & 1) * 64;

    f32x4 acc[4][4];
    #pragma unroll
    for (int i = 0; i < 4; ++i)
        #pragma unroll
        for (int j = 0; j < 4; ++j) acc[i][j] = (f32x4){0.f, 0.f, 0.f, 0.f};

    const short* Ag = A  + (size_t)(r0 + w * 32 + (l >> 2)) * DIM + (l & 3) * 8;
    const short* Wg = Wm + (size_t)(c0 + w * 32 + (l >> 2)) * DIM + (l & 3) * 8;

    glds16(Ag,                    &As[0][(w * 32) * 32]);
    glds16(Ag + (size_t)16 * DIM, &As[0][(w * 32 + 16) * 32]);
    glds16(Wg,                    &Ws[0][(w * 32) * 32]);
    glds16(Wg + (size_t)16 * DIM, &Ws[0][(w * 32 + 16) * 32]);

    int cur = 0;
    for (int k0 = 0; k0 < DIM; k0 += 32) {
        if (k0 + 32 < DIM) {
            int nb = cur ^ 1;
            glds16(Ag + k0 + 32,                    &As[nb][(w * 32) * 32]);
            glds16(Ag + (size_t)16 * DIM + k0 + 32, &As[nb][(w * 32 + 16) * 32]);
            glds16(Wg + k0 + 32,                    &Ws[nb][(w * 32) * 32]);
            glds16(Wg + (size_t)16 * DIM + k0 + 32, &Ws[nb][(w * 32 + 16) * 32]);
            asm volatile("s_waitcnt vmcnt(4)" ::: "memory");   // stage(t) landed
        } else {
            asm volatile("s_waitcnt vmcnt(0)" ::: "memory");   // last tile
        }
        __builtin_amdgcn_sched_barrier(0);
        __builtin_amdgcn_s_barrier();            // all waves' stage(t) visible
        short8 af[4], wf[4];
        #pragma unroll
        for (int mi = 0; mi < 4; ++mi)
            af[mi] = *reinterpret_cast<const short8*>(&As[cur][(wrow + mi * 16 + Li) * 32 + Lg * 8]);
        #pragma unroll
        for (int ni = 0; ni < 4; ++ni)
            wf[ni] = *reinterpret_cast<const short8*>(&Ws[cur][(wcol + ni * 16 + Li) * 32 + Lg * 8]);
        __builtin_amdgcn_s_setprio(1);
        #pragma unroll
        for (int mi = 0; mi < 4; ++mi)
            #pragma unroll
            for (int ni = 0; ni < 4; ++ni)
                acc[mi][ni] = __builtin_amdgcn_mfma_f32_16x16x32_bf16(af[mi], wf[ni], acc[mi][ni], 0, 0, 0);
        __builtin_amdgcn_s_setprio(0);
        __builtin_amdgcn_s_barrier();            // reads done before overwrite
        cur ^= 1;
    }

    #pragma unroll
    for (int mi = 0; mi < 4; ++mi) {
        int rowbase = r0 + wrow + mi * 16 + Lg * 4;
        int b = rowbase / NSEQ;
        int ii = rowbase - b * NSEQ;             // 4-aligned; rr stays in 8-block
        #pragma unroll
        for (int ni = 0; ni < 4; ++ni) {
            int c = c0 + wcol + ni * 16 + Li;
            float bv = bias[c];
            if (mode == 0) {
                int h = c >> 6, e = c & 63;
                size_t base = (size_t)(b * NH + h) * RGN + (size_t)(ii >> 4) * 1024
                            + (e >> 3) * 128 + (ii & 15) * 8 + (e & 7);
                #pragma unroll
                for (int rr = 0; rr < 4; ++rr)
                    qout[base + rr * 8] = f2bf((acc[mi][ni][rr] + bv) * QSC2);
            } else {
                if (c < DIM) {
                    int h = c >> 6, e = c & 63;
                    size_t base = (size_t)(b * NH + h) * RGN + (size_t)(ii >> 4) * 1024
                                + (e >> 3) * 128 + (ii & 15) * 8 + (e & 7);
                    #pragma unroll
                    for (int rr = 0; rr < 4; ++rr)
                        kout[base + rr * 8] = f2bf(acc[mi][ni][rr] + bv);
                } else {
                    int cc = c - DIM;
                    int h = cc >> 6, d = cc & 63;
                    size_t vbase = (size_t)(b * NH + h) * RGN + (size_t)(ii >> 5) * 2048
                                 + (d >> 4) * 512 + ((ii & 31) >> 3) * 128
                                 + (d & 15) * 8 + (ii & 7);
                    union { int w2[2]; u16x4 v; } pk;
                    pk.w2[0] = cvt_pk_bf16(acc[mi][ni][0] + bv, acc[mi][ni][1] + bv);
                    pk.w2[1] = cvt_pk_bf16(acc[mi][ni][2] + bv, acc[mi][ni][3] + bv);
                    *reinterpret_cast<u16x4*>(vtout + vbase) = pk.v;
                }
            }
        }
    }
}

// ------------------------------------------------------------ proj GEMM ---
__global__ __launch_bounds__(256)
void gemm_proj(const short* __restrict__ A, const short* __restrict__ Wm,
               const float* __restrict__ bias, float* __restrict__ out) {
    __shared__ short As[2][128 * 32];
    __shared__ short Ws[2][128 * 32];
    const int t = threadIdx.x;
    const int l = t & 63, w = t >> 6;
    const int Li = l & 15, Lg = l >> 4;
    int orig = blockIdx.x;                       // 294 blocks
    int xcd = orig & 7, idxq = orig >> 3;
    int wg = (xcd < 6 ? xcd * 37 : 222 + (xcd - 6) * 36) + idxq;
    const int c0 = (wg % 6) * 128, r0 = (wg / 6) * 128;
    const int wrow = (w >> 1) * 64, wcol = (w & 1) * 64;

    f32x4 acc[4][4];
    #pragma unroll
    for (int i = 0; i < 4; ++i)
        #pragma unroll
        for (int j = 0; j < 4; ++j) acc[i][j] = (f32x4){0.f, 0.f, 0.f, 0.f};

    const short* Ag = A  + (size_t)(r0 + w * 32 + (l >> 2)) * DIM + (l & 3) * 8;
    const short* Wg = Wm + (size_t)(c0 + w * 32 + (l >> 2)) * DIM + (l & 3) * 8;

    glds16(Ag,                    &As[0][(w * 32) * 32]);
    glds16(Ag + (size_t)16 * DIM, &As[0][(w * 32 + 16) * 32]);
    glds16(Wg,                    &Ws[0][(w * 32) * 32]);
    glds16(Wg + (size_t)16 * DIM, &Ws[0][(w * 32 + 16) * 32]);

    int cur = 0;
    for (int k0 = 0; k0 < DIM; k0 += 32) {
        if (k0 + 32 < DIM) {
            int nb = cur ^ 1;
            glds16(Ag + k0 + 32,                    &As[nb][(w * 32) * 32]);
            glds16(Ag + (size_t)16 * DIM + k0 + 32, &As[nb][(w * 32 + 16) * 32]);
            glds16(Wg + k0 + 32,                    &Ws[nb][(w * 32) * 32]);
            glds16(Wg + (size_t)16 * DIM + k0 + 32, &Ws[nb][(w * 32 + 16) * 32]);
            asm volatile("s_waitcnt vmcnt(4)" ::: "memory");
        } else {
            asm volatile("s_waitcnt vmcnt(0)" ::: "memory");
        }
        __builtin_amdgcn_sched_barrier(0);
        __builtin_amdgcn_s_barrier();
        short8 af[4], wf[4];
        #pragma unroll
        for (int mi = 0; mi < 4; ++mi)
            af[mi] = *reinterpret_cast<const short8*>(&As[cur][(wrow + mi * 16 + Li) * 32 + Lg * 8]);
        #pragma unroll
        for (int ni = 0; ni < 4; ++ni)
            wf[ni] = *reinterpret_cast<const short8*>(&Ws[cur][(wcol + ni * 16 + Li) * 32 + Lg * 8]);
        __builtin_amdgcn_s_setprio(1);
        #pragma unroll
        for (int mi = 0; mi < 4; ++mi)
            #pragma unroll
            for (int ni = 0; ni < 4; ++ni)
                acc[mi][ni] = __builtin_amdgcn_mfma_f32_16x16x32_bf16(af[mi], wf[ni], acc[mi][ni], 0, 0, 0);
        __builtin_amdgcn_s_setprio(0);
        __builtin_amdgcn_s_barrier();
        cur ^= 1;
    }

    #pragma unroll
    for (int mi = 0; mi < 4; ++mi) {
        int rowbase = r0 + wrow + mi * 16 + Lg * 4;
        int b = rowbase / NSEQ;
        int ii = rowbase - b * NSEQ;
        #pragma unroll
        for (int ni = 0; ni < 4; ++ni) {
            int c = c0 + wcol + ni * 16 + Li;
            float bv = bias[c];
            #pragma unroll
            for (int rr = 0; rr < 4; ++rr) {
                int i2 = ii + rr;
                int n = i2 >> 3, tt = i2 & 7;
                out[((size_t)(1 + n) * 32 + b * 8 + tt) * DIM + c] = acc[mi][ni][rr] + bv;
            }
        }
    }
}

// ------------------------------------------------------------ attention ---
// R18: LDS-SHARED K/V. All 4 waves of a block share one q-tile and stream
// identical K/V fragments -> stage each 8KB K + 8KB V tile into LDS ONCE via
// global_load_lds (linear copy; fragment-major layout needs no swizzle) and
// let all waves ds_read it. Cuts attn L2 read traffic 4x (941 -> 235 MB).
// Sync = R17-verified counted-vmcnt two-barrier loop. No early return
// (barriers): tail waves clamp Q loads and skip stores.
__global__ __launch_bounds__(256)
void attn_bf(const short* __restrict__ qf_, const short* __restrict__ kf_,
             const short* __restrict__ vf_, ushort_t* __restrict__ ao) {
    __shared__ short Ks[2][4096];
    __shared__ short Vs[2][4096];
    const int t = threadIdx.x, l = t & 63, w = t >> 6;
    const int li = l & 15, g = l >> 4;
    const int bid = blockIdx.x;                  // 624 = 8 xcd * 78
    const int rest = bid >> 3;                   // 0..77
    const int bh = (bid & 7) + 8 * (rest / 13);  // 6 bh per xcd
    const int qx = rest % 13;
    const int b = bh / NH, h = bh % NH;
    const int q0w = qx * 128 + w * 32;
    const int qrow = (q0w < NSEQ) ? q0w : 0;     // clamp (no early return)
    const size_t RB = (size_t)bh * RGN;
    const short* qR = qf_ + RB + (size_t)(qrow >> 4) * 1024 + l * 8;
    // per-wave staging src: wave w copies shorts [w*1024, (w+1)*1024) of each tile
    const short* kSrc = kf_ + RB + (size_t)(w * 2) * 512 + l * 8;
    const short* vSrc = vf_ + RB + (size_t)(w * 2) * 512 + l * 8;
    short* kD0a = &Ks[0][(w * 2) * 512]; short* kD0b = kD0a + 512;
    short* kD1a = &Ks[1][(w * 2) * 512]; short* kD1b = kD1a + 512;
    short* vD0a = &Vs[0][(w * 2) * 512]; short* vD0b = vD0a + 512;
    short* vD1a = &Vs[1][(w * 2) * 512]; short* vD1b = vD1a + 512;

    short8 qf0[2], qf1[2];
    qf0[0] = *reinterpret_cast<const short8*>(qR);
    qf0[1] = *reinterpret_cast<const short8*>(qR + 512);
    qf1[0] = *reinterpret_cast<const short8*>(qR + 1024);
    qf1[1] = *reinterpret_cast<const short8*>(qR + 1536);

    short8 ones;
    #pragma unroll
    for (int i = 0; i < 8; ++i) ones[i] = (short)0x3F80;   // bf16 1.0

    f32x4 o0[4], o1[4];
    #pragma unroll
    for (int i = 0; i < 4; ++i) {
        o0[i] = (f32x4){0.f, 0.f, 0.f, 0.f};
        o1[i] = (f32x4){0.f, 0.f, 0.f, 0.f};
    }
    f32x4 ol0 = (f32x4){0.f, 0.f, 0.f, 0.f};
    f32x4 ol1 = (f32x4){0.f, 0.f, 0.f, 0.f};
    const int addr0 = (li + ((2 * g) & 3) * 16) * 4;
    const int addr1 = (li + ((2 * g + 1) & 3) * 16) * 4;
    const int gh = g >> 1;

    // prologue: stage tile 0 into buf 0 (4 glds16 per wave)
    glds16(kSrc,       kD0a);  glds16(kSrc + 512,       kD0b);
    glds16(vSrc,       vD0a);  glds16(vSrc + 512,       vD0b);

    int cur = 0;
    for (int mt = 0; mt < 25; ++mt) {
        if (mt < 24) {                           // stage tile mt+1 into buf cur^1
            size_t toff = (size_t)(mt + 1) * 4096;
            if (cur == 0) {
                glds16(kSrc + toff, kD1a);  glds16(kSrc + toff + 512, kD1b);
                glds16(vSrc + toff, vD1a);  glds16(vSrc + toff + 512, vD1b);
            } else {
                glds16(kSrc + toff, kD0a);  glds16(kSrc + toff + 512, kD0b);
                glds16(vSrc + toff, vD0a);  glds16(vSrc + toff + 512, vD0b);
            }
            asm volatile("s_waitcnt vmcnt(4)" ::: "memory");   // tile mt landed
        } else {
            asm volatile("s_waitcnt vmcnt(0)" ::: "memory");
        }
        __builtin_amdgcn_sched_barrier(0);
        __builtin_amdgcn_s_barrier();            // all waves' stage(mt) visible

        // fragment reads (lane-linear b128, all waves share addresses)
        short8 kfr[4][2], vfr[4][2];
        #pragma unroll
        for (int jb = 0; jb < 4; ++jb) {
            kfr[jb][0] = *reinterpret_cast<const short8*>(&Ks[cur][jb * 1024 + l * 8]);
            kfr[jb][1] = *reinterpret_cast<const short8*>(&Ks[cur][jb * 1024 + 512 + l * 8]);
        }
        #pragma unroll
        for (int nb = 0; nb < 4; ++nb) {
            vfr[nb][0] = *reinterpret_cast<const short8*>(&Vs[cur][nb * 512 + l * 8]);
            vfr[nb][1] = *reinterpret_cast<const short8*>(&Vs[cur][2048 + nb * 512 + l * 8]);
        }

        // S^T = K·Q^T
        f32x4 s0[4], s1[4];
        #pragma unroll
        for (int i = 0; i < 4; ++i) {
            s0[i] = (f32x4){0.f, 0.f, 0.f, 0.f};
            s1[i] = (f32x4){0.f, 0.f, 0.f, 0.f};
        }
        __builtin_amdgcn_s_setprio(1);
        #pragma unroll
        for (int jb = 0; jb < 4; ++jb) {
            s0[jb] = __builtin_amdgcn_mfma_f32_16x16x32_bf16(kfr[jb][0], qf0[0], s0[jb], 0, 0, 0);
            s0[jb] = __builtin_amdgcn_mfma_f32_16x16x32_bf16(kfr[jb][1], qf0[1], s0[jb], 0, 0, 0);
            s1[jb] = __builtin_amdgcn_mfma_f32_16x16x32_bf16(kfr[jb][0], qf1[0], s1[jb], 0, 0, 0);
            s1[jb] = __builtin_amdgcn_mfma_f32_16x16x32_bf16(kfr[jb][1], qf1[1], s1[jb], 0, 0, 0);
        }
        __builtin_amdgcn_s_setprio(0);
        if (mt == 24) {                          // tail: rows >= 1568 -> P=0
            #pragma unroll
            for (int r = 0; r < 4; ++r) {
                s0[2][r] = -1e30f; s0[3][r] = -1e30f;
                s1[2][r] = -1e30f; s1[3][r] = -1e30f;
            }
        }

        short8 pf0[2], pf1[2];
        SM_HALF(s0, pf0)
        SM_HALF(s1, pf1)

        // O^T += V^T · P^T  (+ ones-MFMA denominator)
        __builtin_amdgcn_s_setprio(1);
        #pragma unroll
        for (int nb = 0; nb < 4; ++nb)
            #pragma unroll
            for (int j2 = 0; j2 < 2; ++j2) {
                o0[nb] = __builtin_amdgcn_mfma_f32_16x16x32_bf16(vfr[nb][j2], pf0[j2], o0[nb], 0, 0, 0);
                o1[nb] = __builtin_amdgcn_mfma_f32_16x16x32_bf16(vfr[nb][j2], pf1[j2], o1[nb], 0, 0, 0);
            }
        ol0 = __builtin_amdgcn_mfma_f32_16x16x32_bf16(ones, pf0[0], ol0, 0, 0, 0);
        ol0 = __builtin_amdgcn_mfma_f32_16x16x32_bf16(ones, pf0[1], ol0, 0, 0, 0);
        ol1 = __builtin_amdgcn_mfma_f32_16x16x32_bf16(ones, pf1[0], ol1, 0, 0, 0);
        ol1 = __builtin_amdgcn_mfma_f32_16x16x32_bf16(ones, pf1[1], ol1, 0, 0, 0);
        __builtin_amdgcn_s_setprio(0);

        __builtin_amdgcn_s_barrier();            // reads done before overwrite
        cur ^= 1;
    }

    if (q0w < NSEQ) {
        {   // epilogue, half 0 (rows q0w+li)
            float invl = 1.f / ol0[0];
            ushort_t* ob = ao + ((size_t)b * NSEQ + q0w + li) * DIM + h * HD;
            #pragma unroll
            for (int nb = 0; nb < 4; ++nb) {
                union { int w2[2]; u16x4 v; } pk;
                pk.w2[0] = cvt_pk_bf16(o0[nb][0] * invl, o0[nb][1] * invl);
                pk.w2[1] = cvt_pk_bf16(o0[nb][2] * invl, o0[nb][3] * invl);
                *reinterpret_cast<u16x4*>(ob + nb * 16 + g * 4) = pk.v;
            }
        }
        {   // epilogue, half 1 (rows q0w+16+li)
            float invl = 1.f / ol1[0];
            ushort_t* ob = ao + ((size_t)b * NSEQ + q0w + 16 + li) * DIM + h * HD;
            #pragma unroll
            for (int nb = 0; nb < 4; ++nb) {
                union { int w2[2]; u16x4 v; } pk;
                pk.w2[0] = cvt_pk_bf16(o1[nb][0] * invl, o1[nb][1] * invl);
                pk.w2[1] = cvt_pk_bf16(o1[nb][2] * invl, o1[nb][3] * invl);
                *reinterpret_cast<u16x4*>(ob + nb * 16 + g * 4) = pk.v;
            }
        }
    }
}

// --------------------------------------------------------------- launch ---
extern "C" void kernel_launch(void* const* d_in, const int* in_sizes, int n_in,
                              void* d_out, int out_size, void* d_ws, size_t ws_size,
                              hipStream_t stream) {
    const float* s_x    = (const float*)d_in[0];
    const float* t_x    = (const float*)d_in[1];
    const float* csp    = (const float*)d_in[2];
    const float* vsp    = (const float*)d_in[3];
    const float* ctp    = (const float*)d_in[4];
    const float* vtp    = (const float*)d_in[5];
    const float* q_w    = (const float*)d_in[6];
    const float* q_b    = (const float*)d_in[7];
    const float* kv_w   = (const float*)d_in[8];
    const float* kv_b   = (const float*)d_in[9];
    const float* proj_w = (const float*)d_in[10];
    const float* proj_b = (const float*)d_in[11];
    float* out = (float*)d_out;

    const size_t S2 = (size_t)ROWS * DIM;
    const size_t SLACK = 8192;                   // finite cushion for OOB tail fragments
    short* tpat = (short*)d_ws;                  // reused as attn output
    short* spat = tpat + S2;
    short* qbf  = spat + S2;
    short* kbf  = qbf + S2 + SLACK;
    short* vtbf = kbf + S2 + SLACK;
    short* wq   = vtbf + S2 + SLACK;
    short* wkv  = wq + (size_t)DIM * DIM;
    short* wp   = wkv + (size_t)2 * DIM * DIM;

    prep_all<<<5880, 256, 0, stream>>>(
        t_x + (size_t)32 * DIM, s_x + (size_t)64 * DIM, vsp, csp, vtp, ctp,
        q_w, kv_w, proj_w, t_x, tpat, spat, wq, wkv, wp, out);

    gemm_qkv<<<882, 256, 0, stream>>>(tpat, spat, wq, wkv, q_b, kv_b,
                                      (ushort_t*)qbf, (ushort_t*)kbf, (ushort_t*)vtbf);
    attn_bf<<<624, 256, 0, stream>>>(qbf, kbf, vtbf, (ushort_t*)tpat);
    gemm_proj<<<294, 256, 0, stream>>>(tpat, wp, proj_b, out);
}

// Round 19
// 129.021 us; speedup vs baseline: 1.1519x; 1.1519x over previous
//
#include <hip/hip_runtime.h>
#include <hip/hip_bf16.h>

#define DIM 768
#define NH 12
#define HD 64
#define NSEQ 1568
#define ROWS 6272          // B*NSEQ
#define QSC2 0.18033688011112042f   // 0.125 * log2(e) -> softmax in exp2 domain
#define RGN 100352         // per-bh fragment region: 98*1024 = 49*2048 elems

typedef __attribute__((ext_vector_type(8))) short short8;
typedef __attribute__((ext_vector_type(4))) float f32x4;
typedef __attribute__((ext_vector_type(4))) unsigned short u16x4;
typedef unsigned short ushort_t;
typedef unsigned int uint_t;

static __device__ __forceinline__ ushort_t f2bf(float f) {
    union { float f; uint_t u; } c; c.f = f;
    uint_t u = c.u + 0x7fffu + ((c.u >> 16) & 1u);   // RNE
    return (ushort_t)(u >> 16);
}
static __device__ __forceinline__ int cvt_pk_bf16(float lo, float hi) {
    int r;
    asm("v_cvt_pk_bf16_f32 %0, %1, %2" : "=v"(r) : "v"(lo), "v"(hi));
    return r;
}
// async global->LDS, 16B per lane; LDS dest = uniform base + lane*16
static __device__ __forceinline__ void glds16(const short* g, short* l) {
    __builtin_amdgcn_global_load_lds(
        (const __attribute__((address_space(1))) void*)g,
        (__attribute__((address_space(3))) void*)l, 16, 0, 0);
}

// ---- volatile-asm global loads (un-sinkable); counted vmcnt is ours.
#define GLOAD(dst, ptr, OFFB)                                                 \
    asm volatile("global_load_dwordx4 %0, %1, off offset:" #OFFB              \
                 : "=v"(dst) : "v"(ptr))

#define ISSUE_K(KF, KP)                                                       \
    { const short* kp2_ = (KP) + 2048;                                        \
      GLOAD(KF[0][0], (KP), 0);    GLOAD(KF[0][1], (KP), 1024);               \
      GLOAD(KF[1][0], (KP), 2048); GLOAD(KF[1][1], (KP), 3072);               \
      GLOAD(KF[2][0], kp2_, 0);    GLOAD(KF[2][1], kp2_, 1024);               \
      GLOAD(KF[3][0], kp2_, 2048); GLOAD(KF[3][1], kp2_, 3072); }

#define ISSUE_V(VF, VP)                                                       \
    { const short* vp2_ = (VP) + 2048;                                        \
      GLOAD(VF[0][0], (VP), 0);    GLOAD(VF[1][0], (VP), 1024);               \
      GLOAD(VF[2][0], (VP), 2048); GLOAD(VF[3][0], (VP), 3072);               \
      GLOAD(VF[0][1], vp2_, 0);    GLOAD(VF[1][1], vp2_, 1024);               \
      GLOAD(VF[2][1], vp2_, 2048); GLOAD(VF[3][1], vp2_, 3072); }

#define VWAIT0 { asm volatile("s_waitcnt vmcnt(0)" ::: "memory");             \
                 __builtin_amdgcn_sched_barrier(0); }
#define VWAIT8 { asm volatile("s_waitcnt vmcnt(8)" ::: "memory");             \
                 __builtin_amdgcn_sched_barrier(0); }

// softmax+pack+bperm for one q-half (no rowsum: l accumulated via ones-MFMA)
#define SM_HALF(S, PF)                                                        \
    {                                                                         \
        float p_[4][4];                                                       \
        _Pragma("unroll")                                                     \
        for (int jb = 0; jb < 4; ++jb) {                                      \
            _Pragma("unroll")                                                 \
            for (int r = 0; r < 4; ++r)                                       \
                p_[jb][r] = __builtin_amdgcn_exp2f(S[jb][r]);                 \
        }                                                                     \
        int pw_[4][2];                                                        \
        _Pragma("unroll")                                                     \
        for (int jb = 0; jb < 4; ++jb) {                                      \
            pw_[jb][0] = cvt_pk_bf16(p_[jb][0], p_[jb][1]);                   \
            pw_[jb][1] = cvt_pk_bf16(p_[jb][2], p_[jb][3]);                   \
        }                                                                     \
        _Pragma("unroll")                                                     \
        for (int jb2 = 0; jb2 < 2; ++jb2) {                                   \
            int S0_ = gh ? pw_[jb2 * 2 + 1][0] : pw_[jb2 * 2][0];             \
            int S1_ = gh ? pw_[jb2 * 2 + 1][1] : pw_[jb2 * 2][1];             \
            union { int i[4]; short8 s; } fr_;                                \
            fr_.i[0] = __builtin_amdgcn_ds_bpermute(addr0, S0_);              \
            fr_.i[1] = __builtin_amdgcn_ds_bpermute(addr0, S1_);              \
            fr_.i[2] = __builtin_amdgcn_ds_bpermute(addr1, S0_);              \
            fr_.i[3] = __builtin_amdgcn_ds_bpermute(addr1, S1_);              \
            PF[jb2] = fr_.s;                                                  \
        }                                                                     \
    }

// one attention tile, rotated-issue schedule:
//   VWAIT8 [K(t) landed] -> ISSUE_K(t+1) -> QK -> mask -> SM
//   -> VWAIT8 [V(t) landed] -> PV -> ISSUE_V(t+1)
#define ATT_TILE(KF, KFN, DO_ISSUE, MASK)                                     \
    {                                                                         \
        VWAIT8;                                                               \
        if (DO_ISSUE) { ISSUE_K(KFN, kp); kp += 4096; }                       \
        f32x4 s0_[4], s1_[4];                                                 \
        _Pragma("unroll")                                                     \
        for (int i_ = 0; i_ < 4; ++i_) {                                      \
            s0_[i_] = (f32x4){0.f, 0.f, 0.f, 0.f};                            \
            s1_[i_] = (f32x4){0.f, 0.f, 0.f, 0.f};                            \
        }                                                                     \
        __builtin_amdgcn_s_setprio(1);                                        \
        _Pragma("unroll")                                                     \
        for (int jb_ = 0; jb_ < 4; ++jb_) {                                   \
            s0_[jb_] = __builtin_amdgcn_mfma_f32_16x16x32_bf16(KF[jb_][0], qf0[0], s0_[jb_], 0, 0, 0); \
            s0_[jb_] = __builtin_amdgcn_mfma_f32_16x16x32_bf16(KF[jb_][1], qf0[1], s0_[jb_], 0, 0, 0); \
            s1_[jb_] = __builtin_amdgcn_mfma_f32_16x16x32_bf16(KF[jb_][0], qf1[0], s1_[jb_], 0, 0, 0); \
            s1_[jb_] = __builtin_amdgcn_mfma_f32_16x16x32_bf16(KF[jb_][1], qf1[1], s1_[jb_], 0, 0, 0); \
        }                                                                     \
        __builtin_amdgcn_s_setprio(0);                                        \
        if (MASK) {                                                           \
            _Pragma("unroll")                                                 \
            for (int r_ = 0; r_ < 4; ++r_) {                                  \
                s0_[2][r_] = -1e30f; s0_[3][r_] = -1e30f;                     \
                s1_[2][r_] = -1e30f; s1_[3][r_] = -1e30f;                     \
            }                                                                 \
        }                                                                     \
        short8 pf0_[2], pf1_[2];                                              \
        SM_HALF(s0_, pf0_)                                                    \
        SM_HALF(s1_, pf1_)                                                    \
        if (DO_ISSUE) { VWAIT8; } else { VWAIT0; }                            \
        __builtin_amdgcn_s_setprio(1);                                        \
        _Pragma("unroll")                                                     \
        for (int nb_ = 0; nb_ < 4; ++nb_) {                                   \
            _Pragma("unroll")                                                 \
            for (int j2_ = 0; j2_ < 2; ++j2_) {                               \
                o0[nb_] = __builtin_amdgcn_mfma_f32_16x16x32_bf16(vf[nb_][j2_], pf0_[j2_], o0[nb_], 0, 0, 0); \
                o1[nb_] = __builtin_amdgcn_mfma_f32_16x16x32_bf16(vf[nb_][j2_], pf1_[j2_], o1[nb_], 0, 0, 0); \
            }                                                                 \
        }                                                                     \
        ol0 = __builtin_amdgcn_mfma_f32_16x16x32_bf16(ones, pf0_[0], ol0, 0, 0, 0); \
        ol0 = __builtin_amdgcn_mfma_f32_16x16x32_bf16(ones, pf0_[1], ol0, 0, 0, 0); \
        ol1 = __builtin_amdgcn_mfma_f32_16x16x32_bf16(ones, pf1_[0], ol1, 0, 0, 0); \
        ol1 = __builtin_amdgcn_mfma_f32_16x16x32_bf16(ones, pf1_[1], ol1, 0, 0, 0); \
        __builtin_amdgcn_s_setprio(0);                                        \
        if (DO_ISSUE) { ISSUE_V(vf, vp); vp += 4096; }                        \
    }

// ---------------------------------------------------- fused prep+conv+cls --
#define PREP_HALF (ROWS * (DIM / 8))
#define W8 (DIM * DIM / 8)
#define CLS4 (32 * DIM / 4)
// total = 2*PREP_HALF + 4*W8 + CLS4 = 1505280 = 5880*256
__global__ __launch_bounds__(256)
void prep_all(const float* __restrict__ src_t, const float* __restrict__ src_s,
              const float* __restrict__ vsp, const float* __restrict__ csp,
              const float* __restrict__ vtp, const float* __restrict__ ctp,
              const float* __restrict__ qw, const float* __restrict__ kvw,
              const float* __restrict__ pw, const float* __restrict__ txc,
              short* __restrict__ dst_t, short* __restrict__ dst_s,
              short* __restrict__ dq, short* __restrict__ dkv,
              short* __restrict__ dp, float* __restrict__ out_cls) {
    int idx = blockIdx.x * 256 + threadIdx.x;
    if (idx < 2 * PREP_HALF) {
        int sel = idx >= PREP_HALF;
        int i0  = sel ? idx - PREP_HALF : idx;
        const float* src  = sel ? src_s : src_t;
        const float* spos = sel ? csp : vsp;
        const float* tpos = sel ? ctp : vtp;
        short* dst = sel ? dst_s : dst_t;
        int d8  = i0 % (DIM / 8);
        int row = i0 / (DIM / 8);
        int b = row / NSEQ;
        int i = row % NSEQ;
        int n = i >> 3;
        int t = i & 7;
        const float4* s4 = reinterpret_cast<const float4*>(src + ((size_t)n * 32 + b * 8 + t) * DIM + d8 * 8);
        const float4* p4 = reinterpret_cast<const float4*>(spos + (size_t)n * DIM + d8 * 8);
        const float4* q4 = reinterpret_cast<const float4*>(tpos + (size_t)t * DIM + d8 * 8);
        union { int w[4]; short8 v; } o;
        float4 a0 = s4[0], a1 = s4[1], b0 = p4[0], b1 = p4[1], c0 = q4[0], c1 = q4[1];
        o.w[0] = cvt_pk_bf16(a0.x + b0.x + c0.x, a0.y + b0.y + c0.y);
        o.w[1] = cvt_pk_bf16(a0.z + b0.z + c0.z, a0.w + b0.w + c0.w);
        o.w[2] = cvt_pk_bf16(a1.x + b1.x + c1.x, a1.y + b1.y + c1.y);
        o.w[3] = cvt_pk_bf16(a1.z + b1.z + c1.z, a1.w + b1.w + c1.w);
        reinterpret_cast<short8*>(dst)[i0] = o.v;
    } else if (idx < 2 * PREP_HALF + 4 * W8) {
        int i0 = idx - 2 * PREP_HALF;
        const float* src; short* dst; int off;
        if (i0 < W8)            { src = qw;  dst = dq;  off = i0; }
        else if (i0 < 3 * W8)   { src = kvw; dst = dkv; off = i0 - W8; }
        else                    { src = pw;  dst = dp;  off = i0 - 3 * W8; }
        const float4* s4 = reinterpret_cast<const float4*>(src + (size_t)off * 8);
        float4 a0 = s4[0], a1 = s4[1];
        union { int w[4]; short8 v; } o;
        o.w[0] = cvt_pk_bf16(a0.x, a0.y);
        o.w[1] = cvt_pk_bf16(a0.z, a0.w);
        o.w[2] = cvt_pk_bf16(a1.x, a1.y);
        o.w[3] = cvt_pk_bf16(a1.z, a1.w);
        reinterpret_cast<short8*>(dst)[off] = o.v;
    } else {
        int i0 = idx - (2 * PREP_HALF + 4 * W8);
        reinterpret_cast<float4*>(out_cls)[i0] = reinterpret_cast<const float4*>(txc)[i0];
    }
}

// ------------------------------------------------------ fused q+kv GEMM ---
// 2-phase double-buffered (stage-early, one __syncthreads per K-iter).
// Epilogue writes Q/K/V in MFMA-FRAGMENT-MAJOR layouts:
//   Q/K elem (bh,j,e) -> bh*RGN + (j>>4)*1024 + (e>>3)*128 + (j&15)*8 + (e&7)
//   V   elem (bh,d,m) -> bh*RGN + (m>>5)*2048 + (d>>4)*512
//                         + ((m&31)>>3)*128 + (d&15)*8 + (m&7)
__global__ __launch_bounds__(256)
void gemm_qkv(const short* __restrict__ tpat, const short* __restrict__ spat,
              const short* __restrict__ wq, const short* __restrict__ wkv,
              const float* __restrict__ q_b, const float* __restrict__ kv_b,
              ushort_t* __restrict__ qout, ushort_t* __restrict__ kout,
              ushort_t* __restrict__ vtout) {
    __shared__ short As[2][128 * 32];
    __shared__ short Ws[2][128 * 32];
    const int t = threadIdx.x;
    const int l = t & 63, w = t >> 6;
    const int Li = l & 15, Lg = l >> 4;
    int orig = blockIdx.x;                       // 882 blocks
    int xcd = orig & 7, idxq = orig >> 3;
    int wg = (xcd < 2 ? xcd * 111 : 222 + (xcd - 2) * 110) + idxq;
    const int x = wg % 18, y = wg / 18;
    const int mode = (x >= 6);
    const short* A  = mode ? spat : tpat;
    const short* Wm = mode ? wkv : wq;
    const float* bias = mode ? kv_b : q_b;
    const int c0 = (mode ? x - 6 : x) * 128;
    const int r0 = y * 128;
    const int wrow = (w >> 1) * 64, wcol = (w & 1) * 64;

    f32x4 acc[4][4];
    #pragma unroll
    for (int i = 0; i < 4; ++i)
        #pragma unroll
        for (int j = 0; j < 4; ++j) acc[i][j] = (f32x4){0.f, 0.f, 0.f, 0.f};

    const short* Ag = A  + (size_t)(r0 + w * 32 + (l >> 2)) * DIM + (l & 3) * 8;
    const short* Wg = Wm + (size_t)(c0 + w * 32 + (l >> 2)) * DIM + (l & 3) * 8;

    glds16(Ag,                    &As[0][(w * 32) * 32]);
    glds16(Ag + (size_t)16 * DIM, &As[0][(w * 32 + 16) * 32]);
    glds16(Wg,                    &Ws[0][(w * 32) * 32]);
    glds16(Wg + (size_t)16 * DIM, &Ws[0][(w * 32 + 16) * 32]);
    __syncthreads();

    int cur = 0;
    for (int k0 = 0; k0 < DIM; k0 += 32) {
        if (k0 + 32 < DIM) {
            int nb = cur ^ 1;
            glds16(Ag + k0 + 32,                    &As[nb][(w * 32) * 32]);
            glds16(Ag + (size_t)16 * DIM + k0 + 32, &As[nb][(w * 32 + 16) * 32]);
            glds16(Wg + k0 + 32,                    &Ws[nb][(w * 32) * 32]);
            glds16(Wg + (size_t)16 * DIM + k0 + 32, &Ws[nb][(w * 32 + 16) * 32]);
        }
        short8 af[4], wf[4];
        #pragma unroll
        for (int mi = 0; mi < 4; ++mi)
            af[mi] = *reinterpret_cast<const short8*>(&As[cur][(wrow + mi * 16 + Li) * 32 + Lg * 8]);
        #pragma unroll
        for (int ni = 0; ni < 4; ++ni)
            wf[ni] = *reinterpret_cast<const short8*>(&Ws[cur][(wcol + ni * 16 + Li) * 32 + Lg * 8]);
        __builtin_amdgcn_s_setprio(1);
        #pragma unroll
        for (int mi = 0; mi < 4; ++mi)
            #pragma unroll
            for (int ni = 0; ni < 4; ++ni)
                acc[mi][ni] = __builtin_amdgcn_mfma_f32_16x16x32_bf16(af[mi], wf[ni], acc[mi][ni], 0, 0, 0);
        __builtin_amdgcn_s_setprio(0);
        __syncthreads();
        cur ^= 1;
    }

    #pragma unroll
    for (int mi = 0; mi < 4; ++mi) {
        int rowbase = r0 + wrow + mi * 16 + Lg * 4;
        int b = rowbase / NSEQ;
        int ii = rowbase - b * NSEQ;             // 4-aligned; rr stays in 8-block
        #pragma unroll
        for (int ni = 0; ni < 4; ++ni) {
            int c = c0 + wcol + ni * 16 + Li;
            float bv = bias[c];
            if (mode == 0) {
                int h = c >> 6, e = c & 63;
                size_t base = (size_t)(b * NH + h) * RGN + (size_t)(ii >> 4) * 1024
                            + (e >> 3) * 128 + (ii & 15) * 8 + (e & 7);
                #pragma unroll
                for (int rr = 0; rr < 4; ++rr)
                    qout[base + rr * 8] = f2bf((acc[mi][ni][rr] + bv) * QSC2);
            } else {
                if (c < DIM) {
                    int h = c >> 6, e = c & 63;
                    size_t base = (size_t)(b * NH + h) * RGN + (size_t)(ii >> 4) * 1024
                                + (e >> 3) * 128 + (ii & 15) * 8 + (e & 7);
                    #pragma unroll
                    for (int rr = 0; rr < 4; ++rr)
                        kout[base + rr * 8] = f2bf(acc[mi][ni][rr] + bv);
                } else {
                    int cc = c - DIM;
                    int h = cc >> 6, d = cc & 63;
                    size_t vbase = (size_t)(b * NH + h) * RGN + (size_t)(ii >> 5) * 2048
                                 + (d >> 4) * 512 + ((ii & 31) >> 3) * 128
                                 + (d & 15) * 8 + (ii & 7);
                    union { int w2[2]; u16x4 v; } pk;
                    pk.w2[0] = cvt_pk_bf16(acc[mi][ni][0] + bv, acc[mi][ni][1] + bv);
                    pk.w2[1] = cvt_pk_bf16(acc[mi][ni][2] + bv, acc[mi][ni][3] + bv);
                    *reinterpret_cast<u16x4*>(vtout + vbase) = pk.v;
                }
            }
        }
    }
}

// ------------------------------------------------------------ proj GEMM ---
__global__ __launch_bounds__(256)
void gemm_proj(const short* __restrict__ A, const short* __restrict__ Wm,
               const float* __restrict__ bias, float* __restrict__ out) {
    __shared__ short As[2][128 * 32];
    __shared__ short Ws[2][128 * 32];
    const int t = threadIdx.x;
    const int l = t & 63, w = t >> 6;
    const int Li = l & 15, Lg = l >> 4;
    int orig = blockIdx.x;                       // 294 blocks
    int xcd = orig & 7, idxq = orig >> 3;
    int wg = (xcd < 6 ? xcd * 37 : 222 + (xcd - 6) * 36) + idxq;
    const int c0 = (wg % 6) * 128, r0 = (wg / 6) * 128;
    const int wrow = (w >> 1) * 64, wcol = (w & 1) * 64;

    f32x4 acc[4][4];
    #pragma unroll
    for (int i = 0; i < 4; ++i)
        #pragma unroll
        for (int j = 0; j < 4; ++j) acc[i][j] = (f32x4){0.f, 0.f, 0.f, 0.f};

    const short* Ag = A  + (size_t)(r0 + w * 32 + (l >> 2)) * DIM + (l & 3) * 8;
    const short* Wg = Wm + (size_t)(c0 + w * 32 + (l >> 2)) * DIM + (l & 3) * 8;

    glds16(Ag,                    &As[0][(w * 32) * 32]);
    glds16(Ag + (size_t)16 * DIM, &As[0][(w * 32 + 16) * 32]);
    glds16(Wg,                    &Ws[0][(w * 32) * 32]);
    glds16(Wg + (size_t)16 * DIM, &Ws[0][(w * 32 + 16) * 32]);
    __syncthreads();

    int cur = 0;
    for (int k0 = 0; k0 < DIM; k0 += 32) {
        if (k0 + 32 < DIM) {
            int nb = cur ^ 1;
            glds16(Ag + k0 + 32,                    &As[nb][(w * 32) * 32]);
            glds16(Ag + (size_t)16 * DIM + k0 + 32, &As[nb][(w * 32 + 16) * 32]);
            glds16(Wg + k0 + 32,                    &Ws[nb][(w * 32) * 32]);
            glds16(Wg + (size_t)16 * DIM + k0 + 32, &Ws[nb][(w * 32 + 16) * 32]);
        }
        short8 af[4], wf[4];
        #pragma unroll
        for (int mi = 0; mi < 4; ++mi)
            af[mi] = *reinterpret_cast<const short8*>(&As[cur][(wrow + mi * 16 + Li) * 32 + Lg * 8]);
        #pragma unroll
        for (int ni = 0; ni < 4; ++ni)
            wf[ni] = *reinterpret_cast<const short8*>(&Ws[cur][(wcol + ni * 16 + Li) * 32 + Lg * 8]);
        __builtin_amdgcn_s_setprio(1);
        #pragma unroll
        for (int mi = 0; mi < 4; ++mi)
            #pragma unroll
            for (int ni = 0; ni < 4; ++ni)
                acc[mi][ni] = __builtin_amdgcn_mfma_f32_16x16x32_bf16(af[mi], wf[ni], acc[mi][ni], 0, 0, 0);
        __builtin_amdgcn_s_setprio(0);
        __syncthreads();
        cur ^= 1;
    }

    #pragma unroll
    for (int mi = 0; mi < 4; ++mi) {
        int rowbase = r0 + wrow + mi * 16 + Lg * 4;
        int b = rowbase / NSEQ;
        int ii = rowbase - b * NSEQ;
        #pragma unroll
        for (int ni = 0; ni < 4; ++ni) {
            int c = c0 + wcol + ni * 16 + Li;
            float bv = bias[c];
            #pragma unroll
            for (int rr = 0; rr < 4; ++rr) {
                int i2 = ii + rr;
                int n = i2 >> 3, tt = i2 & 7;
                out[((size_t)(1 + n) * 32 + b * 8 + tt) * DIM + c] = acc[mi][ni][rr] + bv;
            }
        }
    }
}

// ------------------------------------------------------------ attention ---
// FINAL (R16 structure): LDS-free fragment-major, barrier-free independent
// waves, rotated counted-vmcnt schedule, ones-MFMA denominator, no-max
// softmax (exact via 1/l). Measured floor ~53.5us for this problem shape.
__global__ __launch_bounds__(256, 2)
void attn_bf(const short* __restrict__ qf_, const short* __restrict__ kf_,
             const short* __restrict__ vf_, ushort_t* __restrict__ ao) {
    const int t = threadIdx.x, l = t & 63, w = t >> 6;
    const int li = l & 15, g = l >> 4;
    const int bid = blockIdx.x;                  // 624 = 8 xcd * 78
    const int rest = bid >> 3;                   // 0..77
    const int bh = (bid & 7) + 8 * (rest / 13);  // 6 bh per xcd
    const int qx = rest % 13;
    const int b = bh / NH, h = bh % NH;
    const int q0w = qx * 128 + w * 32;
    if (q0w >= NSEQ) return;                     // wave-uniform; no barriers
    const size_t RB = (size_t)bh * RGN;
    const short* qR = qf_ + RB + (size_t)(q0w >> 4) * 1024 + l * 8;
    const short* kp = kf_ + RB + l * 8;          // running K tile ptr (+4096/tile)
    const short* vp = vf_ + RB + l * 8;          // running V tile ptr (+4096/tile)

    short8 qf0[2], qf1[2];
    qf0[0] = *reinterpret_cast<const short8*>(qR);
    qf0[1] = *reinterpret_cast<const short8*>(qR + 512);
    qf1[0] = *reinterpret_cast<const short8*>(qR + 1024);
    qf1[1] = *reinterpret_cast<const short8*>(qR + 1536);

    short8 ones;
    #pragma unroll
    for (int i = 0; i < 8; ++i) ones[i] = (short)0x3F80;   // bf16 1.0

    f32x4 o0[4], o1[4];
    #pragma unroll
    for (int i = 0; i < 4; ++i) {
        o0[i] = (f32x4){0.f, 0.f, 0.f, 0.f};
        o1[i] = (f32x4){0.f, 0.f, 0.f, 0.f};
    }
    f32x4 ol0 = (f32x4){0.f, 0.f, 0.f, 0.f};
    f32x4 ol1 = (f32x4){0.f, 0.f, 0.f, 0.f};
    const int addr0 = (li + ((2 * g) & 3) * 16) * 4;
    const int addr1 = (li + ((2 * g + 1) & 3) * 16) * 4;
    const int gh = g >> 1;

    short8 kfA[4][2], kfB[4][2], vf[4][2];

    // prologue: issue K(0) then V(0); 16 loads in flight (K older than V)
    ISSUE_K(kfA, kp); kp += 4096;
    ISSUE_V(vf, vp);  vp += 4096;

    // 25 tiles: 12 x (A,B) with issue, final A(t=24, masked, no issue)
    for (int i = 0; i < 12; ++i) {
        ATT_TILE(kfA, kfB, true, false);
        ATT_TILE(kfB, kfA, true, false);
    }
    ATT_TILE(kfA, kfB, false, true);

    {   // epilogue, half 0 (rows q0w+li)
        float invl = 1.f / ol0[0];
        ushort_t* ob = ao + ((size_t)b * NSEQ + q0w + li) * DIM + h * HD;
        #pragma unroll
        for (int nb = 0; nb < 4; ++nb) {
            union { int w2[2]; u16x4 v; } pk;
            pk.w2[0] = cvt_pk_bf16(o0[nb][0] * invl, o0[nb][1] * invl);
            pk.w2[1] = cvt_pk_bf16(o0[nb][2] * invl, o0[nb][3] * invl);
            *reinterpret_cast<u16x4*>(ob + nb * 16 + g * 4) = pk.v;
        }
    }
    {   // epilogue, half 1 (rows q0w+16+li)
        float invl = 1.f / ol1[0];
        ushort_t* ob = ao + ((size_t)b * NSEQ + q0w + 16 + li) * DIM + h * HD;
        #pragma unroll
        for (int nb = 0; nb < 4; ++nb) {
            union { int w2[2]; u16x4 v; } pk;
            pk.w2[0] = cvt_pk_bf16(o1[nb][0] * invl, o1[nb][1] * invl);
            pk.w2[1] = cvt_pk_bf16(o1[nb][2] * invl, o1[nb][3] * invl);
            *reinterpret_cast<u16x4*>(ob + nb * 16 + g * 4) = pk.v;
        }
    }
}

// --------------------------------------------------------------- launch ---
extern "C" void kernel_launch(void* const* d_in, const int* in_sizes, int n_in,
                              void* d_out, int out_size, void* d_ws, size_t ws_size,
                              hipStream_t stream) {
    const float* s_x    = (const float*)d_in[0];
    const float* t_x    = (const float*)d_in[1];
    const float* csp    = (const float*)d_in[2];
    const float* vsp    = (const float*)d_in[3];
    const float* ctp    = (const float*)d_in[4];
    const float* vtp    = (const float*)d_in[5];
    const float* q_w    = (const float*)d_in[6];
    const float* q_b    = (const float*)d_in[7];
    const float* kv_w   = (const float*)d_in[8];
    const float* kv_b   = (const float*)d_in[9];
    const float* proj_w = (const float*)d_in[10];
    const float* proj_b = (const float*)d_in[11];
    float* out = (float*)d_out;

    const size_t S2 = (size_t)ROWS * DIM;
    const size_t SLACK = 8192;                   // finite cushion for OOB tail fragments
    short* tpat = (short*)d_ws;                  // reused as attn output
    short* spat = tpat + S2;
    short* qbf  = spat + S2;
    short* kbf  = qbf + S2 + SLACK;
    short* vtbf = kbf + S2 + SLACK;
    short* wq   = vtbf + S2 + SLACK;
    short* wkv  = wq + (size_t)DIM * DIM;
    short* wp   = wkv + (size_t)2 * DIM * DIM;

    prep_all<<<5880, 256, 0, stream>>>(
        t_x + (size_t)32 * DIM, s_x + (size_t)64 * DIM, vsp, csp, vtp, ctp,
        q_w, kv_w, proj_w, t_x, tpat, spat, wq, wkv, wp, out);

    gemm_qkv<<<882, 256, 0, stream>>>(tpat, spat, wq, wkv, q_b, kv_b,
                                      (ushort_t*)qbf, (ushort_t*)kbf, (ushort_t*)vtbf);
    attn_bf<<<624, 256, 0, stream>>>(qbf, kbf, vtbf, (ushort_t*)tpat);
    gemm_proj<<<294, 256, 0, stream>>>(tpat, wp, proj_b, out);
}